// Round 7
// baseline (108.264 us; speedup 1.0000x reference)
//
#include <hip/hip_runtime.h>
#include <hip/hip_bf16.h>

#define N 8192
#define D 128
#define HALF_N 4096
// z pre-scaled by sqrt(10*log2e): acc = z.z^T is sim in log2 domain;
// exp(sim) == exp2(acc); sim recovered as acc*LN2 for the pos capture.
#define SQRT_SCALE_LOG2E 3.79828236f
#define LN2 0.693147180559945f

#define NUNITS 1056      // upper-triangle units: 32 row-strips x (64-2*bi) col-pairs
#define COLS_PER_ITER 64
#define LDS_STRIDE 136   // 64 x 128 bf16 tile, padded: conflict-free 8-pass b128

typedef short frag8 __attribute__((ext_vector_type(8)));
typedef float f32x4 __attribute__((ext_vector_type(4)));

// ws layout (floats): pos[N] | sumexp[N] | cnt | pad | z (bf16)
#define OFF_POS 0
#define OFF_SUM N
#define OFF_CNT (2 * N)
#define OFF_Z_BYTES ((2 * N + 64) * 4)   // 16B-aligned

__device__ __forceinline__ unsigned short f2bf(float f) {
    unsigned int u = __float_as_uint(f);
    u += 0x7FFFu + ((u >> 16) & 1u);
    return (unsigned short)(u >> 16);
}

// K1: z = sqrt(10*log2e) * x / max(||x||,eps) (bf16); zero sumexp + counter.
__global__ __launch_bounds__(256) void k_normalize(const float* __restrict__ x,
                                                   unsigned short* __restrict__ z,
                                                   float* __restrict__ wsf) {
    const int row  = blockIdx.x * 4 + (threadIdx.x >> 6);
    const int lane = threadIdx.x & 63;
    float2 v = ((const float2*)x)[row * 64 + lane];
    float s = v.x * v.x + v.y * v.y;
    #pragma unroll
    for (int m = 32; m >= 1; m >>= 1) s += __shfl_xor(s, m);
    float inv = SQRT_SCALE_LOG2E / fmaxf(sqrtf(s), 1e-8f);
    ushort2 o;
    o.x = f2bf(v.x * inv);
    o.y = f2bf(v.y * inv);
    ((ushort2*)z)[row * 64 + lane] = o;
    const int gid = blockIdx.x * 256 + threadIdx.x;
    if (gid < N + 1) wsf[OFF_SUM + gid] = 0.0f;   // sumexp[N] + counter
}

// K2: upper-triangle z.z^T tiles + exp2; row-sums and mirrored col-sums into
// sumexp[] via device atomics. Last block (counter) computes the final mean.
__global__ __launch_bounds__(256, 2) void k_simloss(const unsigned short* __restrict__ z,
                                                    float* __restrict__ sumexp,
                                                    float* __restrict__ pos,
                                                    unsigned int* __restrict__ counter,
                                                    float* __restrict__ out) {
    __shared__ unsigned short lds[COLS_PER_ITER * LDS_STRIDE];  // 17408 B
    __shared__ float pshared[4];
    __shared__ int amLast;

    const int tid  = threadIdx.x;
    const int wave = tid >> 6;
    const int lane = tid & 63;
    const int l15  = lane & 15;
    const int quad = lane >> 4;

    // Decode triangle unit: (bi row-strip of 256, jh col-pair of 128), jh >= 2*bi.
    int b = blockIdx.x, bi = 0;
    while (b >= 64 - 2 * bi) { b -= 64 - 2 * bi; ++bi; }
    const int jh = 2 * bi + b;
    const int wrow = bi * 256 + wave * 64;
    const int colbase0 = jh * 128;

    // A fragments: 4 row-stripes of 16 x K=128, register-resident (64 VGPRs).
    frag8 a[4][4];
    #pragma unroll
    for (int s = 0; s < 4; ++s) {
        const uint4* p = (const uint4*)&z[(wrow + s * 16 + l15) * D + quad * 8];
        #pragma unroll
        for (int q = 0; q < 4; ++q) {
            uint4 t = p[q * 4];
            a[s][q] = *(frag8*)&t;
        }
    }

    float sums[4][4];
    #pragma unroll
    for (int s = 0; s < 4; ++s)
        #pragma unroll
        for (int r = 0; r < 4; ++r) sums[s][r] = 0.0f;

    #pragma unroll
    for (int it = 0; it < 2; ++it) {
        const int colbase = colbase0 + it * COLS_PER_ITER;
        __syncthreads();
        #pragma unroll
        for (int u = 0; u < 4; ++u) {
            int idx = u * 256 + tid;
            int r   = idx >> 4;
            int c8  = idx & 15;
            uint4 t = *(const uint4*)&z[(colbase + r) * D + c8 * 8];
            *(uint4*)&lds[r * LDS_STRIDE + c8 * 8] = t;
        }
        __syncthreads();

        const bool isSelf = (colbase == wrow);
        const bool isPos  = (colbase == wrow + HALF_N);
        if (colbase < wrow) continue;  // lower-triangle wave-tile: skip compute

        const unsigned short* lp = &lds[l15 * LDS_STRIDE + quad * 8];

        #pragma unroll
        for (int c = 0; c < 4; ++c) {
            f32x4 acc[4];
            #pragma unroll
            for (int s = 0; s < 4; ++s) acc[s] = (f32x4){0.f, 0.f, 0.f, 0.f};
            #pragma unroll
            for (int q = 0; q < 4; ++q) {
                frag8 bf = *(const frag8*)(lp + c * 16 * LDS_STRIDE + q * 32);
                #pragma unroll
                for (int s = 0; s < 4; ++s)
                    acc[s] = __builtin_amdgcn_mfma_f32_16x16x32_bf16(a[s][q], bf, acc[s], 0, 0, 0);
            }
            float cs = 0.0f;  // column partial (mirror contribution)
            if (isSelf | isPos) {
                // local diagonal element lives at c==s, l15==quad*4+r
                #pragma unroll
                for (int s = 0; s < 4; ++s)
                    #pragma unroll
                    for (int r = 0; r < 4; ++r) {
                        float v = acc[s][r];
                        float e = __builtin_amdgcn_exp2f(v);
                        if (c == s) {  // compile-time
                            bool hit = (l15 == quad * 4 + r);
                            if (isSelf && hit) e = 0.0f;
                            if (isPos  && hit) pos[wrow + s * 16 + quad * 4 + r] = v * LN2;
                        }
                        sums[s][r] += e;
                        cs += e;
                    }
            } else {
                #pragma unroll
                for (int s = 0; s < 4; ++s)
                    #pragma unroll
                    for (int r = 0; r < 4; ++r) {
                        float e = __builtin_amdgcn_exp2f(acc[s][r]);
                        sums[s][r] += e;
                        cs += e;
                    }
            }
            if (!isSelf) {
                cs += __shfl_xor(cs, 16);
                cs += __shfl_xor(cs, 32);
                if (quad == 0)
                    atomicAdd(&sumexp[colbase + c * 16 + l15], cs);
            }
        }
    }

    // Row-sums: reduce across 16 lanes holding each row, one atomic per row.
    #pragma unroll
    for (int s = 0; s < 4; ++s)
        #pragma unroll
        for (int r = 0; r < 4; ++r) {
            float v = sums[s][r];
            v += __shfl_xor(v, 1);
            v += __shfl_xor(v, 2);
            v += __shfl_xor(v, 4);
            v += __shfl_xor(v, 8);
            if (l15 == 0)
                atomicAdd(&sumexp[wrow + s * 16 + quad * 4 + r], v);
        }

    // Last-block finalize: mean(log(sumexp) - pos), pos mirrored for rows>=N/2.
    __syncthreads();
    if (tid == 0) {
        __threadfence();
        amLast = (atomicAdd(counter, 1u) == NUNITS - 1);
    }
    __syncthreads();
    if (amLast) {
        __threadfence();
        float acc = 0.0f;
        for (int i = tid; i < N; i += 256) {
            float se = atomicAdd(&sumexp[i], 0.0f);              // coherent read
            float pp = atomicAdd(&pos[i & (HALF_N - 1)], 0.0f);  // coherent read
            acc += __logf(se) - pp;
        }
        #pragma unroll
        for (int m = 32; m >= 1; m >>= 1) acc += __shfl_xor(acc, m);
        if (lane == 0) pshared[wave] = acc;
        __syncthreads();
        if (tid == 0)
            out[0] = (pshared[0] + pshared[1] + pshared[2] + pshared[3]) * (1.0f / N);
    }
}

extern "C" void kernel_launch(void* const* d_in, const int* in_sizes, int n_in,
                              void* d_out, int out_size, void* d_ws, size_t ws_size,
                              hipStream_t stream) {
    const float* x = (const float*)d_in[0];
    float* wsf    = (float*)d_ws;
    float* pos    = wsf + OFF_POS;
    float* sumexp = wsf + OFF_SUM;
    unsigned int* counter = (unsigned int*)(wsf + OFF_CNT);
    unsigned short* z = (unsigned short*)((char*)d_ws + OFF_Z_BYTES);

    k_normalize<<<N / 4, 256, 0, stream>>>(x, z, wsf);
    k_simloss<<<NUNITS, 256, 0, stream>>>(z, sumexp, pos, counter, (float*)d_out);
}

// Round 8
// 98.925 us; speedup vs baseline: 1.0944x; 1.0944x over previous
//
#include <hip/hip_runtime.h>
#include <hip/hip_bf16.h>

#define N 8192
#define D 128
#define HALF_N 4096
// z pre-scaled by sqrt(10*log2e): acc = z.z^T is sim in log2 domain;
// exp(sim) == exp2(acc); sim recovered as acc*LN2 for the pos capture.
#define SQRT_SCALE_LOG2E 3.79828236f
#define LN2 0.693147180559945f

#define NUNITS 1056      // upper-triangle units: strip bi has 64-2*bi col-pairs
#define COLS_PER_ITER 64
#define LDS_STRIDE 136   // 64 x 128 bf16 tile, padded: conflict-free 8-pass b128
#define UNIT_STRIDE 384  // per-unit psums: 256 row-partials + 128 col-partials

typedef short frag8 __attribute__((ext_vector_type(8)));
typedef float f32x4 __attribute__((ext_vector_type(4)));

// ws layout (floats): pos[N] | acc0 | cnt | pad | psums[NUNITS*384] | z (bf16)
#define OFF_POS 0
#define OFF_ACC N
#define OFF_CNT (N + 1)
#define OFF_PS  (N + 64)
#define OFF_Z_BYTES ((OFF_PS + NUNITS * UNIT_STRIDE) * 4)  // 16B-aligned

__device__ __forceinline__ unsigned short f2bf(float f) {
    unsigned int u = __float_as_uint(f);
    u += 0x7FFFu + ((u >> 16) & 1u);
    return (unsigned short)(u >> 16);
}

// unit base index for row-strip bi: sum_{k<bi}(64-2k) = bi*(65-bi)
__device__ __forceinline__ int unit_base(int bi) { return bi * (65 - bi); }

// K1: z = sqrt(10*log2e) * x / max(||x||,eps) (bf16); zero acc0 + counter.
__global__ __launch_bounds__(256) void k_normalize(const float* __restrict__ x,
                                                   unsigned short* __restrict__ z,
                                                   float* __restrict__ wsf) {
    const int row  = blockIdx.x * 4 + (threadIdx.x >> 6);
    const int lane = threadIdx.x & 63;
    float2 v = ((const float2*)x)[row * 64 + lane];
    float s = v.x * v.x + v.y * v.y;
    #pragma unroll
    for (int m = 32; m >= 1; m >>= 1) s += __shfl_xor(s, m);
    float inv = SQRT_SCALE_LOG2E / fmaxf(sqrtf(s), 1e-8f);
    ushort2 o;
    o.x = f2bf(v.x * inv);
    o.y = f2bf(v.y * inv);
    ((ushort2*)z)[row * 64 + lane] = o;
    const int gid = blockIdx.x * 256 + threadIdx.x;
    if (gid < 2) wsf[OFF_ACC + gid] = 0.0f;   // acc0, counter
}

// K2: one upper-triangle unit per block; z.z^T tiles + exp2. Row-partials and
// mirrored col-partials written DETERMINISTICALLY to this unit's psums slot —
// no global atomics in the hot path.
__global__ __launch_bounds__(256, 2) void k_simloss(const unsigned short* __restrict__ z,
                                                    float* __restrict__ psums,
                                                    float* __restrict__ pos) {
    __shared__ unsigned short lds[COLS_PER_ITER * LDS_STRIDE];  // 17408 B
    __shared__ float colacc[4][128];                            // wave-private

    const int tid  = threadIdx.x;
    const int wave = tid >> 6;
    const int lane = tid & 63;
    const int l15  = lane & 15;
    const int quad = lane >> 4;

    // Decode triangle unit: (bi row-strip of 256, jh col-pair of 128), jh >= 2*bi.
    int b = blockIdx.x, bi = 0;
    while (b >= 64 - 2 * bi) { b -= 64 - 2 * bi; ++bi; }
    const int jh = 2 * bi + b;
    const int wrow = bi * 256 + wave * 64;
    const int colbase0 = jh * 128;
    float* myps = &psums[blockIdx.x * UNIT_STRIDE];

    // zero wave-private col accumulator (no barrier needed: wave-local)
    colacc[wave][lane] = 0.0f;
    colacc[wave][64 + lane] = 0.0f;

    // A fragments: 4 row-stripes of 16 x K=128, register-resident (64 VGPRs).
    frag8 a[4][4];
    #pragma unroll
    for (int s = 0; s < 4; ++s) {
        const uint4* p = (const uint4*)&z[(wrow + s * 16 + l15) * D + quad * 8];
        #pragma unroll
        for (int q = 0; q < 4; ++q) {
            uint4 t = p[q * 4];
            a[s][q] = *(frag8*)&t;
        }
    }

    float sums[4][4];
    #pragma unroll
    for (int s = 0; s < 4; ++s)
        #pragma unroll
        for (int r = 0; r < 4; ++r) sums[s][r] = 0.0f;

    #pragma unroll
    for (int it = 0; it < 2; ++it) {
        const int colbase = colbase0 + it * COLS_PER_ITER;
        __syncthreads();
        #pragma unroll
        for (int u = 0; u < 4; ++u) {
            int idx = u * 256 + tid;
            int r   = idx >> 4;
            int c8  = idx & 15;
            uint4 t = *(const uint4*)&z[(colbase + r) * D + c8 * 8];
            *(uint4*)&lds[r * LDS_STRIDE + c8 * 8] = t;
        }
        __syncthreads();

        const bool isSelf = (colbase == wrow);
        const bool isPos  = (colbase == wrow + HALF_N);
        if (colbase < wrow) continue;  // lower-triangle wave-tile: skip compute

        const unsigned short* lp = &lds[l15 * LDS_STRIDE + quad * 8];

        #pragma unroll
        for (int c = 0; c < 4; ++c) {
            f32x4 acc[4];
            #pragma unroll
            for (int s = 0; s < 4; ++s) acc[s] = (f32x4){0.f, 0.f, 0.f, 0.f};
            #pragma unroll
            for (int q = 0; q < 4; ++q) {
                frag8 bf = *(const frag8*)(lp + c * 16 * LDS_STRIDE + q * 32);
                #pragma unroll
                for (int s = 0; s < 4; ++s)
                    acc[s] = __builtin_amdgcn_mfma_f32_16x16x32_bf16(a[s][q], bf, acc[s], 0, 0, 0);
            }
            float cs = 0.0f;  // column partial (mirror contribution)
            if (isSelf | isPos) {
                // local diagonal element lives at c==s, l15==quad*4+r
                #pragma unroll
                for (int s = 0; s < 4; ++s)
                    #pragma unroll
                    for (int r = 0; r < 4; ++r) {
                        float v = acc[s][r];
                        float e = __builtin_amdgcn_exp2f(v);
                        if (c == s) {  // compile-time
                            bool hit = (l15 == quad * 4 + r);
                            if (isSelf && hit) e = 0.0f;
                            if (isPos  && hit) pos[wrow + s * 16 + quad * 4 + r] = v * LN2;
                        }
                        sums[s][r] += e;
                        cs += e;
                    }
            } else {
                #pragma unroll
                for (int s = 0; s < 4; ++s)
                    #pragma unroll
                    for (int r = 0; r < 4; ++r) {
                        float e = __builtin_amdgcn_exp2f(acc[s][r]);
                        sums[s][r] += e;
                        cs += e;
                    }
            }
            if (!isSelf) {
                cs += __shfl_xor(cs, 16);
                cs += __shfl_xor(cs, 32);
                if (quad == 0)
                    colacc[wave][it * 64 + c * 16 + l15] += cs;  // wave-private, no race
            }
        }
    }

    // Row partials: reduce across the 16 lanes per row; deterministic store.
    #pragma unroll
    for (int s = 0; s < 4; ++s)
        #pragma unroll
        for (int r = 0; r < 4; ++r) {
            float v = sums[s][r];
            v += __shfl_xor(v, 1);
            v += __shfl_xor(v, 2);
            v += __shfl_xor(v, 4);
            v += __shfl_xor(v, 8);
            if (l15 == 0)
                myps[wave * 64 + s * 16 + quad * 4 + r] = v;
        }

    // Col partials: sum the 4 wave-private arrays; deterministic store.
    __syncthreads();
    if (tid < 128)
        myps[256 + tid] = colacc[0][tid] + colacc[1][tid] + colacc[2][tid] + colacc[3][tid];
}

// K3: per-row gather of partials (closed-form unit indexing, coalesced),
// loss = log(sum) - pos; wave-reduce; last block writes the mean.
__global__ __launch_bounds__(64) void k_rowloss(const float* __restrict__ psums,
                                                const float* __restrict__ pos,
                                                float* __restrict__ acc0,
                                                unsigned int* __restrict__ counter,
                                                float* __restrict__ out) {
    const int r = blockIdx.x * 64 + threadIdx.x;
    const int bi = r >> 8;
    const int ubase = unit_base(bi);
    const int nrow = 64 - 2 * bi;
    float sum = 0.0f;
    for (int k = 0; k < nrow; ++k)
        sum += psums[(ubase + k) * UNIT_STRIDE + (r & 255)];
    const int jh = r >> 7;               // uniform within this 64-row block
    const int ncol = (jh >> 1) + 1;
    for (int b2 = 0; b2 < ncol; ++b2)
        sum += psums[(unit_base(b2) + (jh - 2 * b2)) * UNIT_STRIDE + 256 + (r & 127)];

    float loss = __logf(sum) - pos[r & (HALF_N - 1)];
    #pragma unroll
    for (int m = 32; m >= 1; m >>= 1) loss += __shfl_xor(loss, m);
    if (threadIdx.x == 0) {
        atomicAdd(acc0, loss);
        __threadfence();
        unsigned prev = atomicAdd(counter, 1u);
        if (prev == gridDim.x - 1) {
            float total = atomicAdd(acc0, 0.0f);  // coherent read-back
            out[0] = total * (1.0f / N);
        }
    }
}

extern "C" void kernel_launch(void* const* d_in, const int* in_sizes, int n_in,
                              void* d_out, int out_size, void* d_ws, size_t ws_size,
                              hipStream_t stream) {
    const float* x = (const float*)d_in[0];
    float* wsf    = (float*)d_ws;
    float* pos    = wsf + OFF_POS;
    float* acc0   = wsf + OFF_ACC;
    unsigned int* counter = (unsigned int*)(wsf + OFF_CNT);
    float* psums  = wsf + OFF_PS;
    unsigned short* z = (unsigned short*)((char*)d_ws + OFF_Z_BYTES);

    k_normalize<<<N / 4, 256, 0, stream>>>(x, z, wsf);
    k_simloss<<<NUNITS, 256, 0, stream>>>(z, psums, pos);
    k_rowloss<<<N / 64, 64, 0, stream>>>(psums, pos, acc0, counter, (float*)d_out);
}